// Round 10
// baseline (172.938 us; speedup 1.0000x reference)
//
#include <hip/hip_runtime.h>

#define N_NODES 100000
#define N_EDGES 1600000
#define IN_DIM  64
#define HID     128
#define BN_EPS  1e-5f

// two-level counting sort geometry (64-node buckets)
#define NB        1563     // ceil(100000/64) coarse buckets: dst>>6
#define NPB       64       // nodes per bucket
#define BC_BLOCKS 196      // binning blocks, 8192 edges each
#define EPB4      2048     // int4s per binning block
#define SC_PAD    307200   // 300*1024 >= NB*BC_BLOCKS=306348
#define SC_NBLK   300
#define CONV_BLOCKS 6250   // N_NODES*IN_DIM/4 / 256 exactly

// syrk geometry
#define SYRK_BLOCKS 256
#define SYRK_ROWS   391    // 256*391 >= N_NODES
#define GSZ         4160   // 64*64 G + 64 colsum

#define SRC_MASK  0x1FFFF  // 17 bits (N_NODES < 2^17)
#define LDS_CAP   1536     // max edges/bucket in LDS (mean 1024, sigma 32, +16σ)

// ---------------- 1. fat kernel: binCount (blocks 0..195) + h->bf16 (rest) ----------------
__device__ __forceinline__ unsigned bf16rne(float f) {
    unsigned b = __float_as_uint(f);
    return (b + 0x7FFFu + ((b >> 16) & 1u)) >> 16;
}

__global__ __launch_bounds__(256) void count_conv_kernel(
    const int* __restrict__ dst, int* __restrict__ counts,
    const float* __restrict__ h, unsigned short* __restrict__ h16)
{
    __shared__ int hist[NB];
    const int t = threadIdx.x;
    if (blockIdx.x < BC_BLOCKS) {
        const int blk = blockIdx.x;
        for (int i = t; i < NB; i += 256) hist[i] = 0;
        __syncthreads();
        const int4* d4 = (const int4*)dst;
        const int base = blk * EPB4;
#pragma unroll
        for (int it = 0; it < 8; ++it) {
            int i = base + it * 256 + t;
            if (i < N_EDGES / 4) {
                int4 v = d4[i];
                atomicAdd(&hist[v.x >> 6], 1);
                atomicAdd(&hist[v.y >> 6], 1);
                atomicAdd(&hist[v.z >> 6], 1);
                atomicAdd(&hist[v.w >> 6], 1);
            }
        }
        __syncthreads();
        for (int i = t; i < NB; i += 256) counts[i * BC_BLOCKS + blk] = hist[i];
    } else {
        int i = (blockIdx.x - BC_BLOCKS) * 256 + t;
        if (i < N_NODES * IN_DIM / 4) {
            float4 v = ((const float4*)h)[i];
            uint2 o;
            o.x = bf16rne(v.x) | (bf16rne(v.y) << 16);
            o.y = bf16rne(v.z) | (bf16rne(v.w) << 16);
            ((uint2*)h16)[i] = o;
        }
    }
}

// ---------------- 2. hierarchical exclusive scan of counts ----------------
__global__ __launch_bounds__(256) void scanA_kernel(const int* __restrict__ counts,
                                                    int* __restrict__ blockSums)
{
    __shared__ int lds[256];
    int t = threadIdx.x;
    int4 v = ((const int4*)counts)[blockIdx.x * 256 + t];
    lds[t] = v.x + v.y + v.z + v.w;
    __syncthreads();
    for (int off = 128; off > 0; off >>= 1) {
        if (t < off) lds[t] += lds[t + off];
        __syncthreads();
    }
    if (t == 0) blockSums[blockIdx.x] = lds[0];
}

__global__ __launch_bounds__(512) void scanB_kernel(const int* __restrict__ blockSums,
                                                    int* __restrict__ blockOff)
{
    __shared__ int lds[512];
    int t = threadIdx.x;
    int v = (t < SC_NBLK) ? blockSums[t] : 0;
    lds[t] = v;
    __syncthreads();
    for (int off = 1; off < 512; off <<= 1) {
        int u = (t >= off) ? lds[t - off] : 0;
        __syncthreads();
        lds[t] += u;
        __syncthreads();
    }
    if (t < SC_NBLK) blockOff[t] = lds[t] - v;
}

__global__ __launch_bounds__(256) void scanC_kernel(const int* __restrict__ counts,
                                                    const int* __restrict__ blockOff,
                                                    int* __restrict__ scanned)
{
    __shared__ int lds[256];
    int t = threadIdx.x;
    int idx = blockIdx.x * 256 + t;
    int4 v = ((const int4*)counts)[idx];
    int tsum = v.x + v.y + v.z + v.w;
    lds[t] = tsum;
    __syncthreads();
    for (int off = 1; off < 256; off <<= 1) {
        int u = (t >= off) ? lds[t - off] : 0;
        __syncthreads();
        lds[t] += u;
        __syncthreads();
    }
    int base = blockOff[blockIdx.x] + lds[t] - tsum;
    int i0 = idx * 4;
    scanned[i0 + 0] = base;
    scanned[i0 + 1] = base + v.x;
    scanned[i0 + 2] = base + v.x + v.y;
    scanned[i0 + 3] = base + v.x + v.y + v.z;
}

// ---------------- 3. place packed (dstLocal<<17|src) into coarse buckets ----------------
__global__ __launch_bounds__(256) void binPlace_kernel(const int* __restrict__ src,
                                                       const int* __restrict__ dst,
                                                       const int* __restrict__ scanned,
                                                       int* __restrict__ packed)
{
    __shared__ int cur[NB];
    const int t = threadIdx.x, blk = blockIdx.x;
    for (int i = t; i < NB; i += 256) cur[i] = scanned[i * BC_BLOCKS + blk];
    __syncthreads();
    const int4* d4 = (const int4*)dst;
    const int4* s4 = (const int4*)src;
    const int base = blk * EPB4;
#pragma unroll
    for (int it = 0; it < 8; ++it) {
        int i = base + it * 256 + t;
        if (i < N_EDGES / 4) {
            int4 dv = d4[i];
            int4 sv = s4[i];
            int p0 = atomicAdd(&cur[dv.x >> 6], 1);
            packed[p0] = ((dv.x & 63) << 17) | sv.x;
            int p1 = atomicAdd(&cur[dv.y >> 6], 1);
            packed[p1] = ((dv.y & 63) << 17) | sv.y;
            int p2 = atomicAdd(&cur[dv.z >> 6], 1);
            packed[p2] = ((dv.z & 63) << 17) | sv.z;
            int p3 = atomicAdd(&cur[dv.w >> 6], 1);
            packed[p3] = ((dv.w & 63) << 17) | sv.w;
        }
    }
}

// ---------------- 4. fused in-LDS node sort + paired-lane bf16 gather ----------------
// one block per 64-node bucket, 256 threads = 4 waves (8 blocks/CU resident).
// lane p in [0,32) owns features (2p, 2p+1) packed in one uint of h16u;
// half 0 (lanes 0-31) takes even edges, half 1 odd edges; shfl_xor(32) combines.
__global__ __launch_bounds__(256) void sortAgg_kernel(
    const unsigned* __restrict__ h16u, const int* __restrict__ packed,
    const int* __restrict__ scanned, float* __restrict__ agg)
{
    __shared__ int edges[LDS_CAP];
    __shared__ int hist[NPB], scn[NPB], cur[NPB], offs[NPB + 1];
    const int b = blockIdx.x, t = threadIdx.x;
    const int beg = scanned[b * BC_BLOCKS];
    const int end = scanned[(b + 1) * BC_BLOCKS];
    const int n = end - beg;

    if (t < NPB) hist[t] = 0;
    __syncthreads();
    for (int i = t; i < n; i += 256)
        atomicAdd(&hist[packed[beg + i] >> 17], 1);
    __syncthreads();
    int v = (t < NPB) ? hist[t] : 0;
    if (t < NPB) scn[t] = v;
    __syncthreads();
    for (int off = 1; off < NPB; off <<= 1) {
        int u = (t < NPB && t >= off) ? scn[t - off] : 0;
        __syncthreads();
        if (t < NPB) scn[t] += u;
        __syncthreads();
    }
    if (t < NPB) { offs[t] = scn[t] - v; cur[t] = scn[t] - v; }
    if (t == 0) offs[NPB] = n;
    __syncthreads();
    const bool fast = (n <= LDS_CAP);
    if (fast) {
        for (int i = t; i < n; i += 256) {
            int p = packed[beg + i];
            int pos = atomicAdd(&cur[p >> 17], 1);
            edges[pos] = p & SRC_MASK;
        }
    }
    __syncthreads();

    const int lane = t & 63, w = t >> 6;
    const int p = lane & 31, side = lane >> 5;
    const int node0 = b * NPB;

    for (int ln = w; ln < NPB; ln += 4) {
        int node = node0 + ln;
        if (node >= N_NODES) break;  // ln monotone per wave
        float2 acc = make_float2(0.f, 0.f);
        if (fast) {
            const int o0 = offs[ln];
            const int cnt = offs[ln + 1] - o0;
            int j = side;
            for (; j + 6 < cnt; j += 8) {
                int s0 = edges[o0 + j];
                int s1 = edges[o0 + j + 2];
                int s2 = edges[o0 + j + 4];
                int s3 = edges[o0 + j + 6];
                unsigned u0 = h16u[s0 * 32 + p];
                unsigned u1 = h16u[s1 * 32 + p];
                unsigned u2 = h16u[s2 * 32 + p];
                unsigned u3 = h16u[s3 * 32 + p];
                acc.x += __uint_as_float(u0 << 16);
                acc.y += __uint_as_float(u0 & 0xFFFF0000u);
                acc.x += __uint_as_float(u1 << 16);
                acc.y += __uint_as_float(u1 & 0xFFFF0000u);
                acc.x += __uint_as_float(u2 << 16);
                acc.y += __uint_as_float(u2 & 0xFFFF0000u);
                acc.x += __uint_as_float(u3 << 16);
                acc.y += __uint_as_float(u3 & 0xFFFF0000u);
            }
            for (; j < cnt; j += 2) {
                unsigned u = h16u[edges[o0 + j] * 32 + p];
                acc.x += __uint_as_float(u << 16);
                acc.y += __uint_as_float(u & 0xFFFF0000u);
            }
        } else {
            // overflow fallback (statistically unreachable): filter-scan the run
            for (int i = side; i < n; i += 2) {
                int pk = packed[beg + i];
                if ((pk >> 17) == ln) {
                    unsigned u = h16u[(pk & SRC_MASK) * 32 + p];
                    acc.x += __uint_as_float(u << 16);
                    acc.y += __uint_as_float(u & 0xFFFF0000u);
                }
            }
        }
        acc.x += __shfl_xor(acc.x, 32);
        acc.y += __shfl_xor(acc.y, 32);
        if (side == 0)
            ((float2*)(agg + (size_t)node * IN_DIM))[p] = acc;
    }
}

// ---------------- 5. syrk: G-partials = agg^T agg, colsum partials ----------------
__global__ __launch_bounds__(256) void syrk_kernel(const float* __restrict__ agg,
                                                   float* __restrict__ Gp)
{
    __shared__ float As[32][64];
    const int t = threadIdx.x, blk = blockIdx.x;
    const int row_beg = blk * SYRK_ROWS;
    int row_end = row_beg + SYRK_ROWS;
    if (row_end > N_NODES) row_end = N_NODES;

    const int i0 = (t & 15) * 4, j0 = (t >> 4) * 4;
    float acc[4][4];
#pragma unroll
    for (int i = 0; i < 4; i++)
#pragma unroll
        for (int j = 0; j < 4; j++) acc[i][j] = 0.f;
    float cs = 0.f;

    for (int r0 = row_beg; r0 < row_end; r0 += 32) {
        int nrows = row_end - r0; if (nrows > 32) nrows = 32;
        for (int i = t; i < nrows * 16; i += 256)
            ((float4*)&As[0][0])[i] = ((const float4*)(agg + (size_t)r0 * IN_DIM))[i];
        __syncthreads();
        for (int r = 0; r < nrows; ++r) {
            float4 ai = *(const float4*)&As[r][i0];
            float4 aj = *(const float4*)&As[r][j0];
            acc[0][0] += ai.x * aj.x; acc[0][1] += ai.x * aj.y;
            acc[0][2] += ai.x * aj.z; acc[0][3] += ai.x * aj.w;
            acc[1][0] += ai.y * aj.x; acc[1][1] += ai.y * aj.y;
            acc[1][2] += ai.y * aj.z; acc[1][3] += ai.y * aj.w;
            acc[2][0] += ai.z * aj.x; acc[2][1] += ai.z * aj.y;
            acc[2][2] += ai.z * aj.z; acc[2][3] += ai.z * aj.w;
            acc[3][0] += ai.w * aj.x; acc[3][1] += ai.w * aj.y;
            acc[3][2] += ai.w * aj.z; acc[3][3] += ai.w * aj.w;
        }
        if (t < 64) {
            for (int r = 0; r < nrows; ++r) cs += As[r][t];
        }
        __syncthreads();
    }
    float* gp = Gp + (size_t)blk * GSZ;
#pragma unroll
    for (int i = 0; i < 4; i++)
#pragma unroll
        for (int j = 0; j < 4; j++)
            gp[(i0 + i) * 64 + (j0 + j)] = acc[i][j];
    if (t < 64) gp[4096 + t] = cs;
}

// ---------------- 6. reduce G partials ----------------
__global__ __launch_bounds__(256) void reduceG_kernel(const float* __restrict__ Gp,
                                                      float* __restrict__ G)
{
    int gid = blockIdx.x * 256 + threadIdx.x;
    if (gid < GSZ) {
        float s = 0.f;
        for (int b = 0; b < SYRK_BLOCKS; ++b) s += Gp[(size_t)b * GSZ + gid];
        G[gid] = s;
    }
}

// ---------------- 7. finalize: per-column scale/shift from G ----------------
__global__ __launch_bounds__(256) void finalize_kernel(
    const float* __restrict__ G, const float* __restrict__ W,
    const float* __restrict__ bias, const float* __restrict__ gamma,
    const float* __restrict__ beta, float* __restrict__ scale,
    float* __restrict__ shift)
{
    __shared__ float Gs[4096];
    __shared__ float ss[64];
    __shared__ float part[256];
    const int t = threadIdx.x;
    for (int i = t; i < 4096; i += 256) Gs[i] = G[i];
    if (t < 64) ss[t] = G[4096 + t];
    __syncthreads();

    const int c = t & 127, half = t >> 7;
    float wc[64];
#pragma unroll
    for (int k = 0; k < 64; ++k) wc[k] = W[k * HID + c];

    float p = 0.f;
    for (int k1 = 0; k1 < 32; ++k1) {
        int k1g = half * 32 + k1;
        float dot = 0.f;
#pragma unroll
        for (int k2 = 0; k2 < 64; ++k2) dot += Gs[k1g * 64 + k2] * wc[k2];
        p += W[k1g * HID + c] * dot;
    }
    part[t] = p;
    __syncthreads();
    if (half == 0) {
        float quad = part[c] + part[c + 128];  // w_c^T G w_c
        float tc = 0.f;
#pragma unroll
        for (int k = 0; k < 64; ++k) tc += ss[k] * wc[k];
        const float invN = 1.0f / (float)N_NODES;
        float bc   = bias[c];
        float mean = tc * invN + bc;
        float ez2  = quad * invN + 2.f * bc * tc * invN + bc * bc;
        float var  = ez2 - mean * mean;
        float inv  = rsqrtf(var + BN_EPS);
        float scv  = gamma[c] * inv;
        scale[c] = scv;
        shift[c] = beta[c] - mean * scv;
    }
}

// ---------------- 8. fused GEMM + scale/shift, single output write ----------------
__global__ __launch_bounds__(256) void gemm_out_kernel(
    const float* __restrict__ agg, const float* __restrict__ W,
    const float* __restrict__ scale, const float* __restrict__ shift,
    float* __restrict__ out, int n_blocks)
{
    __shared__ float As[32][64];
    __shared__ float sS[HID], sH[HID];
    const int t = threadIdx.x;
    const int lane = t & 63, wv = t >> 6;
    if (t < HID) { sS[t] = scale[t]; sH[t] = shift[t]; }

    float2 wr[64];
#pragma unroll
    for (int k = 0; k < 64; ++k) wr[k] = ((const float2*)W)[k * 64 + lane];
    __syncthreads();

    for (int tile = blockIdx.x; tile < N_NODES / 32; tile += n_blocks) {
        const int r0 = tile * 32;
        for (int i = t; i < 512; i += 256)
            ((float4*)&As[0][0])[i] = ((const float4*)(agg + (size_t)r0 * IN_DIM))[i];
        __syncthreads();
        const int rbeg = wv * 8;
        for (int r = rbeg; r < rbeg + 8; ++r) {
            const float4* arow = (const float4*)&As[r][0];
            float a0 = 0.f, a1 = 0.f;
#pragma unroll
            for (int kk = 0; kk < 16; ++kk) {
                float4 a = arow[kk];
                a0 += a.x * wr[4 * kk + 0].x; a1 += a.x * wr[4 * kk + 0].y;
                a0 += a.y * wr[4 * kk + 1].x; a1 += a.y * wr[4 * kk + 1].y;
                a0 += a.z * wr[4 * kk + 2].x; a1 += a.z * wr[4 * kk + 2].y;
                a0 += a.w * wr[4 * kk + 3].x; a1 += a.w * wr[4 * kk + 3].y;
            }
            const int c0 = lane * 2;
            float o0 = a0 * sS[c0]     + sH[c0];
            float o1 = a1 * sS[c0 + 1] + sH[c0 + 1];
            ((float2*)out)[(size_t)(r0 + r) * 64 + lane] = make_float2(o0, o1);
        }
        __syncthreads();
    }
}

extern "C" void kernel_launch(void* const* d_in, const int* in_sizes, int n_in,
                              void* d_out, int out_size, void* d_ws, size_t ws_size,
                              hipStream_t stream)
{
    const float* h     = (const float*)d_in[0];
    const int*   src   = (const int*)d_in[1];
    const int*   dst   = (const int*)d_in[2];
    const float* W     = (const float*)d_in[3];
    const float* b     = (const float*)d_in[4];
    const float* gamma = (const float*)d_in[5];
    const float* beta  = (const float*)d_in[6];

    float* out = (float*)d_out;

    // ---- workspace layout ----
    // persistent: agg (25.6 MB) | h16 (12.8 MB) | G | scale | shift
    float* agg  = (float*)d_ws;
    unsigned short* h16 = (unsigned short*)(agg + (size_t)N_NODES * IN_DIM);
    float* G     = (float*)(h16 + (size_t)N_NODES * IN_DIM);
    float* scale = G + GSZ;
    float* shift = scale + HID;
    // transient (time-shared): counts | blockSums | blockOff | scanned | packed (~8.9 MB)
    int*  counts    = (int*)(shift + HID);
    int*  blockSums = counts + SC_PAD;
    int*  blockOff  = blockSums + 512;
    int*  scanned   = blockOff + 512;
    int*  packed    = scanned + SC_PAD;          // N_EDGES ints
    float* Gp       = (float*)counts;            // aliases sort transients (dead by syrk)

    // binCount writes every real (bucket,block) entry; only the pad tail needs zeroing
    hipMemsetAsync(counts + NB * BC_BLOCKS, 0,
                   (SC_PAD - NB * BC_BLOCKS) * sizeof(int), stream);

    count_conv_kernel<<<BC_BLOCKS + CONV_BLOCKS, 256, 0, stream>>>(dst, counts, h, h16);
    scanA_kernel<<<SC_NBLK, 256, 0, stream>>>(counts, blockSums);
    scanB_kernel<<<1, 512, 0, stream>>>(blockSums, blockOff);
    scanC_kernel<<<SC_NBLK, 256, 0, stream>>>(counts, blockOff, scanned);
    binPlace_kernel<<<BC_BLOCKS, 256, 0, stream>>>(src, dst, scanned, packed);
    sortAgg_kernel<<<NB, 256, 0, stream>>>((const unsigned*)h16, packed, scanned, agg);
    syrk_kernel<<<SYRK_BLOCKS, 256, 0, stream>>>(agg, Gp);
    reduceG_kernel<<<(GSZ + 255) / 256, 256, 0, stream>>>(Gp, G);
    finalize_kernel<<<1, 256, 0, stream>>>(G, W, b, gamma, beta, scale, shift);
    gemm_out_kernel<<<1024, 256, 0, stream>>>(agg, W, scale, shift, out, 1024);
}

// Round 11
// 158.203 us; speedup vs baseline: 1.0931x; 1.0931x over previous
//
#include <hip/hip_runtime.h>

#define N_NODES 100000
#define N_EDGES 1600000
#define IN_DIM  64
#define HID     128
#define BN_EPS  1e-5f

// two-level counting sort geometry (round-9 proven: 128-node buckets)
#define NB        782      // coarse buckets: dst>>7
#define BC_BLOCKS 196      // binning blocks, 8192 edges each
#define EPB4      2048     // int4s per binning block
#define SC_PAD    153600   // NB*BC_BLOCKS=153272 padded
#define SC_NBLK   150
#define CONV_BLOCKS 6250   // N_NODES*IN_DIM/4 / 256 exactly

// syrk geometry
#define SYRK_BLOCKS 256
#define SYRK_ROWS   391    // 256*391 >= N_NODES
#define GSZ         4160   // 64*64 G + 64 colsum

#define SRC_MASK  0x1FFFF  // 17 bits (N_NODES < 2^17)
#define LDS_CAP   3072     // max edges per bucket staged in LDS (mean 2048, sigma 45)

// ---------------- 1. fat kernel: binCount (blocks 0..195) + h->bf16 (rest) ----------------
__device__ __forceinline__ unsigned bf16rne(float f) {
    unsigned b = __float_as_uint(f);
    return (b + 0x7FFFu + ((b >> 16) & 1u)) >> 16;
}

__global__ __launch_bounds__(256) void count_conv_kernel(
    const int* __restrict__ dst, int* __restrict__ counts,
    const float* __restrict__ h, unsigned short* __restrict__ h16)
{
    __shared__ int hist[NB];
    const int t = threadIdx.x;
    if (blockIdx.x < BC_BLOCKS) {
        const int blk = blockIdx.x;
        for (int i = t; i < NB; i += 256) hist[i] = 0;
        __syncthreads();
        const int4* d4 = (const int4*)dst;
        const int base = blk * EPB4;
#pragma unroll
        for (int it = 0; it < 8; ++it) {
            int i = base + it * 256 + t;
            if (i < N_EDGES / 4) {
                int4 v = d4[i];
                atomicAdd(&hist[v.x >> 7], 1);
                atomicAdd(&hist[v.y >> 7], 1);
                atomicAdd(&hist[v.z >> 7], 1);
                atomicAdd(&hist[v.w >> 7], 1);
            }
        }
        __syncthreads();
        for (int i = t; i < NB; i += 256) counts[i * BC_BLOCKS + blk] = hist[i];
    } else {
        int i = (blockIdx.x - BC_BLOCKS) * 256 + t;
        if (i < N_NODES * IN_DIM / 4) {
            float4 v = ((const float4*)h)[i];
            uint2 o;
            o.x = bf16rne(v.x) | (bf16rne(v.y) << 16);
            o.y = bf16rne(v.z) | (bf16rne(v.w) << 16);
            ((uint2*)h16)[i] = o;
        }
    }
}

// ---------------- 2. hierarchical exclusive scan of counts ----------------
__global__ __launch_bounds__(256) void scanA_kernel(const int* __restrict__ counts,
                                                    int* __restrict__ blockSums)
{
    __shared__ int lds[256];
    int t = threadIdx.x;
    int4 v = ((const int4*)counts)[blockIdx.x * 256 + t];
    lds[t] = v.x + v.y + v.z + v.w;
    __syncthreads();
    for (int off = 128; off > 0; off >>= 1) {
        if (t < off) lds[t] += lds[t + off];
        __syncthreads();
    }
    if (t == 0) blockSums[blockIdx.x] = lds[0];
}

__global__ __launch_bounds__(256) void scanB_kernel(const int* __restrict__ blockSums,
                                                    int* __restrict__ blockOff)
{
    __shared__ int lds[256];
    int t = threadIdx.x;
    int v = (t < SC_NBLK) ? blockSums[t] : 0;
    lds[t] = v;
    __syncthreads();
    for (int off = 1; off < 256; off <<= 1) {
        int u = (t >= off) ? lds[t - off] : 0;
        __syncthreads();
        lds[t] += u;
        __syncthreads();
    }
    if (t < SC_NBLK) blockOff[t] = lds[t] - v;
}

__global__ __launch_bounds__(256) void scanC_kernel(const int* __restrict__ counts,
                                                    const int* __restrict__ blockOff,
                                                    int* __restrict__ scanned)
{
    __shared__ int lds[256];
    int t = threadIdx.x;
    int idx = blockIdx.x * 256 + t;
    int4 v = ((const int4*)counts)[idx];
    int tsum = v.x + v.y + v.z + v.w;
    lds[t] = tsum;
    __syncthreads();
    for (int off = 1; off < 256; off <<= 1) {
        int u = (t >= off) ? lds[t - off] : 0;
        __syncthreads();
        lds[t] += u;
        __syncthreads();
    }
    int base = blockOff[blockIdx.x] + lds[t] - tsum;
    int i0 = idx * 4;
    scanned[i0 + 0] = base;
    scanned[i0 + 1] = base + v.x;
    scanned[i0 + 2] = base + v.x + v.y;
    scanned[i0 + 3] = base + v.x + v.y + v.z;
}

// ---------------- 3. place packed (dstLocal<<17|src) into coarse buckets ----------------
__global__ __launch_bounds__(256) void binPlace_kernel(const int* __restrict__ src,
                                                       const int* __restrict__ dst,
                                                       const int* __restrict__ scanned,
                                                       int* __restrict__ packed)
{
    __shared__ int cur[NB];
    const int t = threadIdx.x, blk = blockIdx.x;
    for (int i = t; i < NB; i += 256) cur[i] = scanned[i * BC_BLOCKS + blk];
    __syncthreads();
    const int4* d4 = (const int4*)dst;
    const int4* s4 = (const int4*)src;
    const int base = blk * EPB4;
#pragma unroll
    for (int it = 0; it < 8; ++it) {
        int i = base + it * 256 + t;
        if (i < N_EDGES / 4) {
            int4 dv = d4[i];
            int4 sv = s4[i];
            int p0 = atomicAdd(&cur[dv.x >> 7], 1);
            packed[p0] = ((dv.x & 127) << 17) | sv.x;
            int p1 = atomicAdd(&cur[dv.y >> 7], 1);
            packed[p1] = ((dv.y & 127) << 17) | sv.y;
            int p2 = atomicAdd(&cur[dv.z >> 7], 1);
            packed[p2] = ((dv.z & 127) << 17) | sv.z;
            int p3 = atomicAdd(&cur[dv.w >> 7], 1);
            packed[p3] = ((dv.w & 127) << 17) | sv.w;
        }
    }
}

// ---------------- 4. fused in-LDS node sort + paired-lane bf16 gather ----------------
__global__ __launch_bounds__(512) void sortAgg_kernel(
    const unsigned* __restrict__ h16u, const int* __restrict__ packed,
    const int* __restrict__ scanned, float* __restrict__ agg)
{
    __shared__ int edges[LDS_CAP];
    __shared__ int hist[128], scn[128], cur[128], offs[129];
    const int b = blockIdx.x, t = threadIdx.x;
    const int beg = scanned[b * BC_BLOCKS];
    const int end = scanned[(b + 1) * BC_BLOCKS];
    const int n = end - beg;

    if (t < 128) hist[t] = 0;
    __syncthreads();
    for (int i = t; i < n; i += 512)
        atomicAdd(&hist[packed[beg + i] >> 17], 1);
    __syncthreads();
    int v = (t < 128) ? hist[t] : 0;
    if (t < 128) scn[t] = v;
    __syncthreads();
    for (int off = 1; off < 128; off <<= 1) {
        int u = (t < 128 && t >= off) ? scn[t - off] : 0;
        __syncthreads();
        if (t < 128) scn[t] += u;
        __syncthreads();
    }
    if (t < 128) { offs[t] = scn[t] - v; cur[t] = scn[t] - v; }
    if (t == 0) offs[128] = n;
    __syncthreads();
    const bool fast = (n <= LDS_CAP);
    if (fast) {
        for (int i = t; i < n; i += 512) {
            int p = packed[beg + i];
            int pos = atomicAdd(&cur[p >> 17], 1);
            edges[pos] = p & SRC_MASK;
        }
    }
    __syncthreads();

    const int lane = t & 63, w = t >> 6;
    const int p = lane & 31, side = lane >> 5;
    const int node0 = b << 7;

    for (int ln = w; ln < 128; ln += 8) {
        int node = node0 + ln;
        if (node >= N_NODES) break;  // ln monotone per wave
        float2 acc = make_float2(0.f, 0.f);
        if (fast) {
            const int o0 = offs[ln];
            const int cnt = offs[ln + 1] - o0;
            int j = side;
            for (; j + 6 < cnt; j += 8) {
                int s0 = edges[o0 + j];
                int s1 = edges[o0 + j + 2];
                int s2 = edges[o0 + j + 4];
                int s3 = edges[o0 + j + 6];
                unsigned u0 = h16u[s0 * 32 + p];
                unsigned u1 = h16u[s1 * 32 + p];
                unsigned u2 = h16u[s2 * 32 + p];
                unsigned u3 = h16u[s3 * 32 + p];
                acc.x += __uint_as_float(u0 << 16);
                acc.y += __uint_as_float(u0 & 0xFFFF0000u);
                acc.x += __uint_as_float(u1 << 16);
                acc.y += __uint_as_float(u1 & 0xFFFF0000u);
                acc.x += __uint_as_float(u2 << 16);
                acc.y += __uint_as_float(u2 & 0xFFFF0000u);
                acc.x += __uint_as_float(u3 << 16);
                acc.y += __uint_as_float(u3 & 0xFFFF0000u);
            }
            for (; j < cnt; j += 2) {
                unsigned u = h16u[edges[o0 + j] * 32 + p];
                acc.x += __uint_as_float(u << 16);
                acc.y += __uint_as_float(u & 0xFFFF0000u);
            }
        } else {
            for (int i = side; i < n; i += 2) {
                int pk = packed[beg + i];
                if ((pk >> 17) == ln) {
                    unsigned u = h16u[(pk & SRC_MASK) * 32 + p];
                    acc.x += __uint_as_float(u << 16);
                    acc.y += __uint_as_float(u & 0xFFFF0000u);
                }
            }
        }
        acc.x += __shfl_xor(acc.x, 32);
        acc.y += __shfl_xor(acc.y, 32);
        if (side == 0)
            ((float2*)(agg + (size_t)node * IN_DIM))[p] = acc;
    }
}

// ---------------- 5. syrk: G-partials = agg^T agg, colsum partials ----------------
__global__ __launch_bounds__(256) void syrk_kernel(const float* __restrict__ agg,
                                                   float* __restrict__ Gp)
{
    __shared__ float As[32][64];
    const int t = threadIdx.x, blk = blockIdx.x;
    const int row_beg = blk * SYRK_ROWS;
    int row_end = row_beg + SYRK_ROWS;
    if (row_end > N_NODES) row_end = N_NODES;

    const int i0 = (t & 15) * 4, j0 = (t >> 4) * 4;
    float acc[4][4];
#pragma unroll
    for (int i = 0; i < 4; i++)
#pragma unroll
        for (int j = 0; j < 4; j++) acc[i][j] = 0.f;
    float cs = 0.f;

    for (int r0 = row_beg; r0 < row_end; r0 += 32) {
        int nrows = row_end - r0; if (nrows > 32) nrows = 32;
        for (int i = t; i < nrows * 16; i += 256)
            ((float4*)&As[0][0])[i] = ((const float4*)(agg + (size_t)r0 * IN_DIM))[i];
        __syncthreads();
        for (int r = 0; r < nrows; ++r) {
            float4 ai = *(const float4*)&As[r][i0];
            float4 aj = *(const float4*)&As[r][j0];
            acc[0][0] += ai.x * aj.x; acc[0][1] += ai.x * aj.y;
            acc[0][2] += ai.x * aj.z; acc[0][3] += ai.x * aj.w;
            acc[1][0] += ai.y * aj.x; acc[1][1] += ai.y * aj.y;
            acc[1][2] += ai.y * aj.z; acc[1][3] += ai.y * aj.w;
            acc[2][0] += ai.z * aj.x; acc[2][1] += ai.z * aj.y;
            acc[2][2] += ai.z * aj.z; acc[2][3] += ai.z * aj.w;
            acc[3][0] += ai.w * aj.x; acc[3][1] += ai.w * aj.y;
            acc[3][2] += ai.w * aj.z; acc[3][3] += ai.w * aj.w;
        }
        if (t < 64) {
            for (int r = 0; r < nrows; ++r) cs += As[r][t];
        }
        __syncthreads();
    }
    float* gp = Gp + (size_t)blk * GSZ;
#pragma unroll
    for (int i = 0; i < 4; i++)
#pragma unroll
        for (int j = 0; j < 4; j++)
            gp[(i0 + i) * 64 + (j0 + j)] = acc[i][j];
    if (t < 64) gp[4096 + t] = cs;
}

// ---------------- 6. reduce G partials ----------------
__global__ __launch_bounds__(256) void reduceG_kernel(const float* __restrict__ Gp,
                                                      float* __restrict__ G)
{
    int gid = blockIdx.x * 256 + threadIdx.x;
    if (gid < GSZ) {
        float s = 0.f;
        for (int b = 0; b < SYRK_BLOCKS; ++b) s += Gp[(size_t)b * GSZ + gid];
        G[gid] = s;
    }
}

// ---------------- 7. finalize: per-column scale/shift from G ----------------
__global__ __launch_bounds__(256) void finalize_kernel(
    const float* __restrict__ G, const float* __restrict__ W,
    const float* __restrict__ bias, const float* __restrict__ gamma,
    const float* __restrict__ beta, float* __restrict__ scale,
    float* __restrict__ shift)
{
    __shared__ float Gs[4096];
    __shared__ float ss[64];
    __shared__ float part[256];
    const int t = threadIdx.x;
    for (int i = t; i < 4096; i += 256) Gs[i] = G[i];
    if (t < 64) ss[t] = G[4096 + t];
    __syncthreads();

    const int c = t & 127, half = t >> 7;
    float wc[64];
#pragma unroll
    for (int k = 0; k < 64; ++k) wc[k] = W[k * HID + c];

    float p = 0.f;
    for (int k1 = 0; k1 < 32; ++k1) {
        int k1g = half * 32 + k1;
        float dot = 0.f;
#pragma unroll
        for (int k2 = 0; k2 < 64; ++k2) dot += Gs[k1g * 64 + k2] * wc[k2];
        p += W[k1g * HID + c] * dot;
    }
    part[t] = p;
    __syncthreads();
    if (half == 0) {
        float quad = part[c] + part[c + 128];  // w_c^T G w_c
        float tc = 0.f;
#pragma unroll
        for (int k = 0; k < 64; ++k) tc += ss[k] * wc[k];
        const float invN = 1.0f / (float)N_NODES;
        float bc   = bias[c];
        float mean = tc * invN + bc;
        float ez2  = quad * invN + 2.f * bc * tc * invN + bc * bc;
        float var  = ez2 - mean * mean;
        float inv  = rsqrtf(var + BN_EPS);
        float scv  = gamma[c] * inv;
        scale[c] = scv;
        shift[c] = beta[c] - mean * scv;
    }
}

// ---------------- 8. GEMM + scale/shift: LDS W + transposed-A, 4x4 per thread ----------------
// one block per 32-row tile (3125 blocks). thread: rows r0..r0+3, cols c4..c4+3.
// per k: ds_read_b128(W row) + ds_read_b128(A column via transpose) + 16 FMA.
#define AST_LD 36   // row stride of Ast in floats (144 B: 16B-aligned, odd bank group)
__global__ __launch_bounds__(256) void gemm_out_kernel(
    const float* __restrict__ agg, const float* __restrict__ W,
    const float* __restrict__ scale, const float* __restrict__ shift,
    float* __restrict__ out)
{
    __shared__ float Ws[IN_DIM][HID];        // 32 KB
    __shared__ float Ast[IN_DIM][AST_LD];    // 9 KB, Ast[k][row]
    const int t = threadIdx.x;
    const int tile = blockIdx.x;
    const int rowbase = tile * 32;

    // stage W (coalesced float4)
    {
        const float4* s4 = (const float4*)W;
        float4* d4 = (float4*)&Ws[0][0];
#pragma unroll
        for (int i = 0; i < (IN_DIM * HID / 4) / 256; ++i)
            d4[t + i * 256] = s4[t + i * 256];
    }
    // stage A transposed: linear float4 l -> row=l>>4, kg=l&15
    {
        const float4* s4 = (const float4*)(agg + (size_t)rowbase * IN_DIM);
#pragma unroll
        for (int it = 0; it < 2; ++it) {
            int l = t + it * 256;
            float4 a = s4[l];
            int row = l >> 4, kg = (l & 15) * 4;
            Ast[kg + 0][row] = a.x;
            Ast[kg + 1][row] = a.y;
            Ast[kg + 2][row] = a.z;
            Ast[kg + 3][row] = a.w;
        }
    }
    __syncthreads();

    const int c4 = (t & 31) * 4;     // 4 consecutive cols
    const int r0 = (t >> 5) * 4;     // 4 consecutive rows

    float acc[4][4];
#pragma unroll
    for (int i = 0; i < 4; i++)
#pragma unroll
        for (int j = 0; j < 4; j++) acc[i][j] = 0.f;

#pragma unroll 8
    for (int k = 0; k < IN_DIM; ++k) {
        float4 w4 = *(const float4*)&Ws[k][c4];
        float4 a4 = *(const float4*)&Ast[k][r0];
        acc[0][0] += a4.x * w4.x; acc[0][1] += a4.x * w4.y;
        acc[0][2] += a4.x * w4.z; acc[0][3] += a4.x * w4.w;
        acc[1][0] += a4.y * w4.x; acc[1][1] += a4.y * w4.y;
        acc[1][2] += a4.y * w4.z; acc[1][3] += a4.y * w4.w;
        acc[2][0] += a4.z * w4.x; acc[2][1] += a4.z * w4.y;
        acc[2][2] += a4.z * w4.z; acc[2][3] += a4.z * w4.w;
        acc[3][0] += a4.w * w4.x; acc[3][1] += a4.w * w4.y;
        acc[3][2] += a4.w * w4.z; acc[3][3] += a4.w * w4.w;
    }

    const float4 sc4 = ((const float4*)scale)[t & 31];
    const float4 sh4 = ((const float4*)shift)[t & 31];
#pragma unroll
    for (int i = 0; i < 4; ++i) {
        float4 o;
        o.x = acc[i][0] * sc4.x + sh4.x;
        o.y = acc[i][1] * sc4.y + sh4.y;
        o.z = acc[i][2] * sc4.z + sh4.z;
        o.w = acc[i][3] * sc4.w + sh4.w;
        *(float4*)&out[(size_t)(rowbase + r0 + i) * HID + c4] = o;
    }
}

extern "C" void kernel_launch(void* const* d_in, const int* in_sizes, int n_in,
                              void* d_out, int out_size, void* d_ws, size_t ws_size,
                              hipStream_t stream)
{
    const float* h     = (const float*)d_in[0];
    const int*   src   = (const int*)d_in[1];
    const int*   dst   = (const int*)d_in[2];
    const float* W     = (const float*)d_in[3];
    const float* b     = (const float*)d_in[4];
    const float* gamma = (const float*)d_in[5];
    const float* beta  = (const float*)d_in[6];

    float* out = (float*)d_out;

    // ---- workspace layout ----
    // persistent: agg (25.6 MB) | h16 (12.8 MB) | G | scale | shift
    float* agg  = (float*)d_ws;
    unsigned short* h16 = (unsigned short*)(agg + (size_t)N_NODES * IN_DIM);
    float* G     = (float*)(h16 + (size_t)N_NODES * IN_DIM);
    float* scale = G + GSZ;
    float* shift = scale + HID;
    // transient (time-shared): counts | blockSums | blockOff | scanned | packed (~7.7 MB)
    int*  counts    = (int*)(shift + HID);
    int*  blockSums = counts + SC_PAD;
    int*  blockOff  = blockSums + 256;
    int*  scanned   = blockOff + 256;
    int*  packed    = scanned + SC_PAD;          // N_EDGES ints
    float* Gp       = (float*)counts;            // aliases sort transients (dead by syrk)

    // binCount writes every real (bucket,block) entry; zero only the pad tail
    hipMemsetAsync(counts + NB * BC_BLOCKS, 0,
                   (SC_PAD - NB * BC_BLOCKS) * sizeof(int), stream);

    count_conv_kernel<<<BC_BLOCKS + CONV_BLOCKS, 256, 0, stream>>>(dst, counts, h, h16);
    scanA_kernel<<<SC_NBLK, 256, 0, stream>>>(counts, blockSums);
    scanB_kernel<<<1, 256, 0, stream>>>(blockSums, blockOff);
    scanC_kernel<<<SC_NBLK, 256, 0, stream>>>(counts, blockOff, scanned);
    binPlace_kernel<<<BC_BLOCKS, 256, 0, stream>>>(src, dst, scanned, packed);
    sortAgg_kernel<<<NB, 512, 0, stream>>>((const unsigned*)h16, packed, scanned, agg);
    syrk_kernel<<<SYRK_BLOCKS, 256, 0, stream>>>(agg, Gp);
    reduceG_kernel<<<(GSZ + 255) / 256, 256, 0, stream>>>(Gp, G);
    finalize_kernel<<<1, 256, 0, stream>>>(G, W, b, gamma, beta, scale, shift);
    gemm_out_kernel<<<N_NODES / 32, 256, 0, stream>>>(agg, W, scale, shift, out);
}

// Round 12
// 154.342 us; speedup vs baseline: 1.1205x; 1.0250x over previous
//
#include <hip/hip_runtime.h>

#define N_NODES 100000
#define N_EDGES 1600000
#define IN_DIM  64
#define HID     128
#define BN_EPS  1e-5f

// two-level counting sort geometry (128-node buckets)
#define NB        782      // coarse buckets: dst>>7
#define BC_BLOCKS 196      // binning blocks, 8192 edges each
#define EPB4      2048     // int4s per binning block
#define SC_PAD    153600   // NB*BC_BLOCKS=153272 padded
#define SC_NBLK   150
#define CONV_BLOCKS 6250   // N_NODES*IN_DIM/4 / 256 exactly

// syrk geometry
#define SYRK_BLOCKS 256
#define SYRK_ROWS   391    // 256*391 >= N_NODES
#define GSZ         4160   // 64*64 G + 64 colsum

#define SRC_MASK  0x1FFFF  // 17 bits (N_NODES < 2^17)
#define LDS_CAP   3072     // max edges per bucket staged in LDS (mean 2048, sigma 45)

// ---------------- 1. fat kernel: binCount + h->bf16 + pad-tail zero ----------------
__device__ __forceinline__ unsigned bf16rne(float f) {
    unsigned b = __float_as_uint(f);
    return (b + 0x7FFFu + ((b >> 16) & 1u)) >> 16;
}

__global__ __launch_bounds__(256) void count_conv_kernel(
    const int* __restrict__ dst, int* __restrict__ counts,
    const float* __restrict__ h, unsigned short* __restrict__ h16)
{
    __shared__ int hist[NB];
    const int t = threadIdx.x;
    if (blockIdx.x < BC_BLOCKS) {
        const int blk = blockIdx.x;
        for (int i = t; i < NB; i += 256) hist[i] = 0;
        __syncthreads();
        const int4* d4 = (const int4*)dst;
        const int base = blk * EPB4;
#pragma unroll
        for (int it = 0; it < 8; ++it) {
            int i = base + it * 256 + t;
            if (i < N_EDGES / 4) {
                int4 v = d4[i];
                atomicAdd(&hist[v.x >> 7], 1);
                atomicAdd(&hist[v.y >> 7], 1);
                atomicAdd(&hist[v.z >> 7], 1);
                atomicAdd(&hist[v.w >> 7], 1);
            }
        }
        __syncthreads();
        for (int i = t; i < NB; i += 256) counts[i * BC_BLOCKS + blk] = hist[i];
    } else if (blockIdx.x < BC_BLOCKS + CONV_BLOCKS) {
        int i = (blockIdx.x - BC_BLOCKS) * 256 + t;
        if (i < N_NODES * IN_DIM / 4) {
            float4 v = ((const float4*)h)[i];
            uint2 o;
            o.x = bf16rne(v.x) | (bf16rne(v.y) << 16);
            o.y = bf16rne(v.z) | (bf16rne(v.w) << 16);
            ((uint2*)h16)[i] = o;
        }
    } else {
        // zero the scan pad tail (replaces a ~40us rocclr fill dispatch)
        for (int i = NB * BC_BLOCKS + t; i < SC_PAD; i += 256) counts[i] = 0;
    }
}

// ---------------- 2. hierarchical exclusive scan of counts ----------------
__global__ __launch_bounds__(256) void scanA_kernel(const int* __restrict__ counts,
                                                    int* __restrict__ blockSums)
{
    __shared__ int lds[256];
    int t = threadIdx.x;
    int4 v = ((const int4*)counts)[blockIdx.x * 256 + t];
    lds[t] = v.x + v.y + v.z + v.w;
    __syncthreads();
    for (int off = 128; off > 0; off >>= 1) {
        if (t < off) lds[t] += lds[t + off];
        __syncthreads();
    }
    if (t == 0) blockSums[blockIdx.x] = lds[0];
}

__global__ __launch_bounds__(256) void scanB_kernel(const int* __restrict__ blockSums,
                                                    int* __restrict__ blockOff)
{
    __shared__ int lds[256];
    int t = threadIdx.x;
    int v = (t < SC_NBLK) ? blockSums[t] : 0;
    lds[t] = v;
    __syncthreads();
    for (int off = 1; off < 256; off <<= 1) {
        int u = (t >= off) ? lds[t - off] : 0;
        __syncthreads();
        lds[t] += u;
        __syncthreads();
    }
    if (t < SC_NBLK) blockOff[t] = lds[t] - v;
}

__global__ __launch_bounds__(256) void scanC_kernel(const int* __restrict__ counts,
                                                    const int* __restrict__ blockOff,
                                                    int* __restrict__ scanned)
{
    __shared__ int lds[256];
    int t = threadIdx.x;
    int idx = blockIdx.x * 256 + t;
    int4 v = ((const int4*)counts)[idx];
    int tsum = v.x + v.y + v.z + v.w;
    lds[t] = tsum;
    __syncthreads();
    for (int off = 1; off < 256; off <<= 1) {
        int u = (t >= off) ? lds[t - off] : 0;
        __syncthreads();
        lds[t] += u;
        __syncthreads();
    }
    int base = blockOff[blockIdx.x] + lds[t] - tsum;
    int i0 = idx * 4;
    scanned[i0 + 0] = base;
    scanned[i0 + 1] = base + v.x;
    scanned[i0 + 2] = base + v.x + v.y;
    scanned[i0 + 3] = base + v.x + v.y + v.z;
}

// ---------------- 3. place packed (dstLocal<<17|src) into coarse buckets ----------------
__global__ __launch_bounds__(256) void binPlace_kernel(const int* __restrict__ src,
                                                       const int* __restrict__ dst,
                                                       const int* __restrict__ scanned,
                                                       int* __restrict__ packed)
{
    __shared__ int cur[NB];
    const int t = threadIdx.x, blk = blockIdx.x;
    for (int i = t; i < NB; i += 256) cur[i] = scanned[i * BC_BLOCKS + blk];
    __syncthreads();
    const int4* d4 = (const int4*)dst;
    const int4* s4 = (const int4*)src;
    const int base = blk * EPB4;
#pragma unroll
    for (int it = 0; it < 8; ++it) {
        int i = base + it * 256 + t;
        if (i < N_EDGES / 4) {
            int4 dv = d4[i];
            int4 sv = s4[i];
            int p0 = atomicAdd(&cur[dv.x >> 7], 1);
            packed[p0] = ((dv.x & 127) << 17) | sv.x;
            int p1 = atomicAdd(&cur[dv.y >> 7], 1);
            packed[p1] = ((dv.y & 127) << 17) | sv.y;
            int p2 = atomicAdd(&cur[dv.z >> 7], 1);
            packed[p2] = ((dv.z & 127) << 17) | sv.z;
            int p3 = atomicAdd(&cur[dv.w >> 7], 1);
            packed[p3] = ((dv.w & 127) << 17) | sv.w;
        }
    }
}

// ---------------- 4. fused in-LDS node sort + paired-lane bf16 gather ----------------
__global__ __launch_bounds__(512) void sortAgg_kernel(
    const unsigned* __restrict__ h16u, const int* __restrict__ packed,
    const int* __restrict__ scanned, float* __restrict__ agg)
{
    __shared__ int edges[LDS_CAP];
    __shared__ int hist[128], scn[128], cur[128], offs[129];
    const int b = blockIdx.x, t = threadIdx.x;
    const int beg = scanned[b * BC_BLOCKS];
    const int end = scanned[(b + 1) * BC_BLOCKS];
    const int n = end - beg;

    if (t < 128) hist[t] = 0;
    __syncthreads();
    for (int i = t; i < n; i += 512)
        atomicAdd(&hist[packed[beg + i] >> 17], 1);
    __syncthreads();
    int v = (t < 128) ? hist[t] : 0;
    if (t < 128) scn[t] = v;
    __syncthreads();
    for (int off = 1; off < 128; off <<= 1) {
        int u = (t < 128 && t >= off) ? scn[t - off] : 0;
        __syncthreads();
        if (t < 128) scn[t] += u;
        __syncthreads();
    }
    if (t < 128) { offs[t] = scn[t] - v; cur[t] = scn[t] - v; }
    if (t == 0) offs[128] = n;
    __syncthreads();
    const bool fast = (n <= LDS_CAP);
    if (fast) {
        for (int i = t; i < n; i += 512) {
            int p = packed[beg + i];
            int pos = atomicAdd(&cur[p >> 17], 1);
            edges[pos] = p & SRC_MASK;
        }
    }
    __syncthreads();

    const int lane = t & 63, w = t >> 6;
    const int p = lane & 31, side = lane >> 5;
    const int node0 = b << 7;

    for (int ln = w; ln < 128; ln += 8) {
        int node = node0 + ln;
        if (node >= N_NODES) break;  // ln monotone per wave
        float2 acc = make_float2(0.f, 0.f);
        if (fast) {
            const int o0 = offs[ln];
            const int cnt = offs[ln + 1] - o0;
            int j = side;
            for (; j + 6 < cnt; j += 8) {
                int s0 = edges[o0 + j];
                int s1 = edges[o0 + j + 2];
                int s2 = edges[o0 + j + 4];
                int s3 = edges[o0 + j + 6];
                unsigned u0 = h16u[s0 * 32 + p];
                unsigned u1 = h16u[s1 * 32 + p];
                unsigned u2 = h16u[s2 * 32 + p];
                unsigned u3 = h16u[s3 * 32 + p];
                acc.x += __uint_as_float(u0 << 16);
                acc.y += __uint_as_float(u0 & 0xFFFF0000u);
                acc.x += __uint_as_float(u1 << 16);
                acc.y += __uint_as_float(u1 & 0xFFFF0000u);
                acc.x += __uint_as_float(u2 << 16);
                acc.y += __uint_as_float(u2 & 0xFFFF0000u);
                acc.x += __uint_as_float(u3 << 16);
                acc.y += __uint_as_float(u3 & 0xFFFF0000u);
            }
            for (; j < cnt; j += 2) {
                unsigned u = h16u[edges[o0 + j] * 32 + p];
                acc.x += __uint_as_float(u << 16);
                acc.y += __uint_as_float(u & 0xFFFF0000u);
            }
        } else {
            for (int i = side; i < n; i += 2) {
                int pk = packed[beg + i];
                if ((pk >> 17) == ln) {
                    unsigned u = h16u[(pk & SRC_MASK) * 32 + p];
                    acc.x += __uint_as_float(u << 16);
                    acc.y += __uint_as_float(u & 0xFFFF0000u);
                }
            }
        }
        acc.x += __shfl_xor(acc.x, 32);
        acc.y += __shfl_xor(acc.y, 32);
        if (side == 0)
            ((float2*)(agg + (size_t)node * IN_DIM))[p] = acc;
    }
}

// ---------------- 5. syrk: G-partials = agg^T agg, colsum partials ----------------
__global__ __launch_bounds__(256) void syrk_kernel(const float* __restrict__ agg,
                                                   float* __restrict__ Gp)
{
    __shared__ float As[32][64];
    const int t = threadIdx.x, blk = blockIdx.x;
    const int row_beg = blk * SYRK_ROWS;
    int row_end = row_beg + SYRK_ROWS;
    if (row_end > N_NODES) row_end = N_NODES;

    const int i0 = (t & 15) * 4, j0 = (t >> 4) * 4;
    float acc[4][4];
#pragma unroll
    for (int i = 0; i < 4; i++)
#pragma unroll
        for (int j = 0; j < 4; j++) acc[i][j] = 0.f;
    float cs = 0.f;

    for (int r0 = row_beg; r0 < row_end; r0 += 32) {
        int nrows = row_end - r0; if (nrows > 32) nrows = 32;
        for (int i = t; i < nrows * 16; i += 256)
            ((float4*)&As[0][0])[i] = ((const float4*)(agg + (size_t)r0 * IN_DIM))[i];
        __syncthreads();
        for (int r = 0; r < nrows; ++r) {
            float4 ai = *(const float4*)&As[r][i0];
            float4 aj = *(const float4*)&As[r][j0];
            acc[0][0] += ai.x * aj.x; acc[0][1] += ai.x * aj.y;
            acc[0][2] += ai.x * aj.z; acc[0][3] += ai.x * aj.w;
            acc[1][0] += ai.y * aj.x; acc[1][1] += ai.y * aj.y;
            acc[1][2] += ai.y * aj.z; acc[1][3] += ai.y * aj.w;
            acc[2][0] += ai.z * aj.x; acc[2][1] += ai.z * aj.y;
            acc[2][2] += ai.z * aj.z; acc[2][3] += ai.z * aj.w;
            acc[3][0] += ai.w * aj.x; acc[3][1] += ai.w * aj.y;
            acc[3][2] += ai.w * aj.z; acc[3][3] += ai.w * aj.w;
        }
        if (t < 64) {
            for (int r = 0; r < nrows; ++r) cs += As[r][t];
        }
        __syncthreads();
    }
    float* gp = Gp + (size_t)blk * GSZ;
#pragma unroll
    for (int i = 0; i < 4; i++)
#pragma unroll
        for (int j = 0; j < 4; j++)
            gp[(i0 + i) * 64 + (j0 + j)] = acc[i][j];
    if (t < 64) gp[4096 + t] = cs;
}

// ---------------- 6. reduce G partials ----------------
__global__ __launch_bounds__(256) void reduceG_kernel(const float* __restrict__ Gp,
                                                      float* __restrict__ G)
{
    int gid = blockIdx.x * 256 + threadIdx.x;
    if (gid < GSZ) {
        float s = 0.f;
        for (int b = 0; b < SYRK_BLOCKS; ++b) s += Gp[(size_t)b * GSZ + gid];
        G[gid] = s;
    }
}

// ---------------- 7. finalize: per-column scale/shift from G ----------------
__global__ __launch_bounds__(256) void finalize_kernel(
    const float* __restrict__ G, const float* __restrict__ W,
    const float* __restrict__ bias, const float* __restrict__ gamma,
    const float* __restrict__ beta, float* __restrict__ scale,
    float* __restrict__ shift)
{
    __shared__ float Gs[4096];
    __shared__ float ss[64];
    __shared__ float part[256];
    const int t = threadIdx.x;
    for (int i = t; i < 4096; i += 256) Gs[i] = G[i];
    if (t < 64) ss[t] = G[4096 + t];
    __syncthreads();

    const int c = t & 127, half = t >> 7;
    float wc[64];
#pragma unroll
    for (int k = 0; k < 64; ++k) wc[k] = W[k * HID + c];

    float p = 0.f;
    for (int k1 = 0; k1 < 32; ++k1) {
        int k1g = half * 32 + k1;
        float dot = 0.f;
#pragma unroll
        for (int k2 = 0; k2 < 64; ++k2) dot += Gs[k1g * 64 + k2] * wc[k2];
        p += W[k1g * HID + c] * dot;
    }
    part[t] = p;
    __syncthreads();
    if (half == 0) {
        float quad = part[c] + part[c + 128];  // w_c^T G w_c
        float tc = 0.f;
#pragma unroll
        for (int k = 0; k < 64; ++k) tc += ss[k] * wc[k];
        const float invN = 1.0f / (float)N_NODES;
        float bc   = bias[c];
        float mean = tc * invN + bc;
        float ez2  = quad * invN + 2.f * bc * tc * invN + bc * bc;
        float var  = ez2 - mean * mean;
        float inv  = rsqrtf(var + BN_EPS);
        float scv  = gamma[c] * inv;
        scale[c] = scv;
        shift[c] = beta[c] - mean * scv;
    }
}

// ---------------- 8. GEMM + scale/shift: LDS W + transposed-A, 4x4 per thread ----------------
#define AST_LD 36   // row stride of Ast in floats (144 B: 16B-aligned, odd bank group)
__global__ __launch_bounds__(256) void gemm_out_kernel(
    const float* __restrict__ agg, const float* __restrict__ W,
    const float* __restrict__ scale, const float* __restrict__ shift,
    float* __restrict__ out)
{
    __shared__ float Ws[IN_DIM][HID];        // 32 KB
    __shared__ float Ast[IN_DIM][AST_LD];    // 9 KB, Ast[k][row]
    const int t = threadIdx.x;
    const int tile = blockIdx.x;
    const int rowbase = tile * 32;

    {
        const float4* s4 = (const float4*)W;
        float4* d4 = (float4*)&Ws[0][0];
#pragma unroll
        for (int i = 0; i < (IN_DIM * HID / 4) / 256; ++i)
            d4[t + i * 256] = s4[t + i * 256];
    }
    {
        const float4* s4 = (const float4*)(agg + (size_t)rowbase * IN_DIM);
#pragma unroll
        for (int it = 0; it < 2; ++it) {
            int l = t + it * 256;
            float4 a = s4[l];
            int row = l >> 4, kg = (l & 15) * 4;
            Ast[kg + 0][row] = a.x;
            Ast[kg + 1][row] = a.y;
            Ast[kg + 2][row] = a.z;
            Ast[kg + 3][row] = a.w;
        }
    }
    __syncthreads();

    const int c4 = (t & 31) * 4;
    const int r0 = (t >> 5) * 4;

    float acc[4][4];
#pragma unroll
    for (int i = 0; i < 4; i++)
#pragma unroll
        for (int j = 0; j < 4; j++) acc[i][j] = 0.f;

#pragma unroll 8
    for (int k = 0; k < IN_DIM; ++k) {
        float4 w4 = *(const float4*)&Ws[k][c4];
        float4 a4 = *(const float4*)&Ast[k][r0];
        acc[0][0] += a4.x * w4.x; acc[0][1] += a4.x * w4.y;
        acc[0][2] += a4.x * w4.z; acc[0][3] += a4.x * w4.w;
        acc[1][0] += a4.y * w4.x; acc[1][1] += a4.y * w4.y;
        acc[1][2] += a4.y * w4.z; acc[1][3] += a4.y * w4.w;
        acc[2][0] += a4.z * w4.x; acc[2][1] += a4.z * w4.y;
        acc[2][2] += a4.z * w4.z; acc[2][3] += a4.z * w4.w;
        acc[3][0] += a4.w * w4.x; acc[3][1] += a4.w * w4.y;
        acc[3][2] += a4.w * w4.z; acc[3][3] += a4.w * w4.w;
    }

    const float4 sc4 = ((const float4*)scale)[t & 31];
    const float4 sh4 = ((const float4*)shift)[t & 31];
#pragma unroll
    for (int i = 0; i < 4; ++i) {
        float4 o;
        o.x = acc[i][0] * sc4.x + sh4.x;
        o.y = acc[i][1] * sc4.y + sh4.y;
        o.z = acc[i][2] * sc4.z + sh4.z;
        o.w = acc[i][3] * sc4.w + sh4.w;
        *(float4*)&out[(size_t)(rowbase + r0 + i) * HID + c4] = o;
    }
}

extern "C" void kernel_launch(void* const* d_in, const int* in_sizes, int n_in,
                              void* d_out, int out_size, void* d_ws, size_t ws_size,
                              hipStream_t stream)
{
    const float* h     = (const float*)d_in[0];
    const int*   src   = (const int*)d_in[1];
    const int*   dst   = (const int*)d_in[2];
    const float* W     = (const float*)d_in[3];
    const float* b     = (const float*)d_in[4];
    const float* gamma = (const float*)d_in[5];
    const float* beta  = (const float*)d_in[6];

    float* out = (float*)d_out;

    // ---- workspace layout ----
    float* agg  = (float*)d_ws;
    unsigned short* h16 = (unsigned short*)(agg + (size_t)N_NODES * IN_DIM);
    float* G     = (float*)(h16 + (size_t)N_NODES * IN_DIM);
    float* scale = G + GSZ;
    float* shift = scale + HID;
    int*  counts    = (int*)(shift + HID);
    int*  blockSums = counts + SC_PAD;
    int*  blockOff  = blockSums + 256;
    int*  scanned   = blockOff + 256;
    int*  packed    = scanned + SC_PAD;          // N_EDGES ints
    float* Gp       = (float*)counts;            // aliases sort transients (dead by syrk)

    // no hipMemsetAsync: pad tail zeroed by count_conv_kernel's last block

    count_conv_kernel<<<BC_BLOCKS + CONV_BLOCKS + 1, 256, 0, stream>>>(dst, counts,
                                                                       h, h16);
    scanA_kernel<<<SC_NBLK, 256, 0, stream>>>(counts, blockSums);
    scanB_kernel<<<1, 256, 0, stream>>>(blockSums, blockOff);
    scanC_kernel<<<SC_NBLK, 256, 0, stream>>>(counts, blockOff, scanned);
    binPlace_kernel<<<BC_BLOCKS, 256, 0, stream>>>(src, dst, scanned, packed);
    sortAgg_kernel<<<NB, 512, 0, stream>>>((const unsigned*)h16, packed, scanned, agg);
    syrk_kernel<<<SYRK_BLOCKS, 256, 0, stream>>>(agg, Gp);
    reduceG_kernel<<<(GSZ + 255) / 256, 256, 0, stream>>>(Gp, G);
    finalize_kernel<<<1, 256, 0, stream>>>(G, W, b, gamma, beta, scale, shift);
    gemm_out_kernel<<<N_NODES / 32, 256, 0, stream>>>(agg, W, scale, shift, out);
}

// Round 13
// 152.444 us; speedup vs baseline: 1.1344x; 1.0124x over previous
//
#include <hip/hip_runtime.h>

#define N_NODES 100000
#define N_EDGES 1600000
#define IN_DIM  64
#define HID     128
#define BN_EPS  1e-5f

// two-level counting sort geometry (128-node buckets)
#define NB        782      // coarse buckets: dst>>7
#define BC_BLOCKS 196      // binning blocks, 8192 edges each
#define EPB4      2048     // int4s per binning block
#define SC_PAD    153600   // NB*BC_BLOCKS=153272 padded
#define SC_NBLK   150
#define CONV_BLOCKS 6250   // N_NODES*IN_DIM/4 / 256 exactly

// syrk geometry
#define SYRK_BLOCKS 256
#define SYRK_ROWS   391    // 256*391 >= N_NODES
#define GSZ         4160   // 64*64 G + 64 colsum

#define SRC_MASK  0x1FFFF  // 17 bits (N_NODES < 2^17)
#define LDS_CAP   3072     // max edges per bucket staged in LDS (mean 2048, sigma 45)

// ---------------- 1. fat kernel: binCount + h->bf16 + pad-tail zero ----------------
__device__ __forceinline__ unsigned bf16rne(float f) {
    unsigned b = __float_as_uint(f);
    return (b + 0x7FFFu + ((b >> 16) & 1u)) >> 16;
}

__global__ __launch_bounds__(256) void count_conv_kernel(
    const int* __restrict__ dst, int* __restrict__ counts,
    const float* __restrict__ h, unsigned short* __restrict__ h16)
{
    __shared__ int hist[NB];
    const int t = threadIdx.x;
    if (blockIdx.x < BC_BLOCKS) {
        const int blk = blockIdx.x;
        for (int i = t; i < NB; i += 256) hist[i] = 0;
        __syncthreads();
        const int4* d4 = (const int4*)dst;
        const int base = blk * EPB4;
#pragma unroll
        for (int it = 0; it < 8; ++it) {
            int i = base + it * 256 + t;
            if (i < N_EDGES / 4) {
                int4 v = d4[i];
                atomicAdd(&hist[v.x >> 7], 1);
                atomicAdd(&hist[v.y >> 7], 1);
                atomicAdd(&hist[v.z >> 7], 1);
                atomicAdd(&hist[v.w >> 7], 1);
            }
        }
        __syncthreads();
        for (int i = t; i < NB; i += 256) counts[i * BC_BLOCKS + blk] = hist[i];
    } else if (blockIdx.x < BC_BLOCKS + CONV_BLOCKS) {
        int i = (blockIdx.x - BC_BLOCKS) * 256 + t;
        if (i < N_NODES * IN_DIM / 4) {
            float4 v = ((const float4*)h)[i];
            uint2 o;
            o.x = bf16rne(v.x) | (bf16rne(v.y) << 16);
            o.y = bf16rne(v.z) | (bf16rne(v.w) << 16);
            ((uint2*)h16)[i] = o;
        }
    } else {
        // zero the scan pad tail (replaces a rocclr fill dispatch)
        for (int i = NB * BC_BLOCKS + t; i < SC_PAD; i += 256) counts[i] = 0;
    }
}

// ---------------- 2. hierarchical exclusive scan of counts ----------------
__global__ __launch_bounds__(256) void scanA_kernel(const int* __restrict__ counts,
                                                    int* __restrict__ blockSums)
{
    __shared__ int lds[256];
    int t = threadIdx.x;
    int4 v = ((const int4*)counts)[blockIdx.x * 256 + t];
    lds[t] = v.x + v.y + v.z + v.w;
    __syncthreads();
    for (int off = 128; off > 0; off >>= 1) {
        if (t < off) lds[t] += lds[t + off];
        __syncthreads();
    }
    if (t == 0) blockSums[blockIdx.x] = lds[0];
}

__global__ __launch_bounds__(256) void scanB_kernel(const int* __restrict__ blockSums,
                                                    int* __restrict__ blockOff)
{
    __shared__ int lds[256];
    int t = threadIdx.x;
    int v = (t < SC_NBLK) ? blockSums[t] : 0;
    lds[t] = v;
    __syncthreads();
    for (int off = 1; off < 256; off <<= 1) {
        int u = (t >= off) ? lds[t - off] : 0;
        __syncthreads();
        lds[t] += u;
        __syncthreads();
    }
    if (t < SC_NBLK) blockOff[t] = lds[t] - v;
}

__global__ __launch_bounds__(256) void scanC_kernel(const int* __restrict__ counts,
                                                    const int* __restrict__ blockOff,
                                                    int* __restrict__ scanned)
{
    __shared__ int lds[256];
    int t = threadIdx.x;
    int idx = blockIdx.x * 256 + t;
    int4 v = ((const int4*)counts)[idx];
    int tsum = v.x + v.y + v.z + v.w;
    lds[t] = tsum;
    __syncthreads();
    for (int off = 1; off < 256; off <<= 1) {
        int u = (t >= off) ? lds[t - off] : 0;
        __syncthreads();
        lds[t] += u;
        __syncthreads();
    }
    int base = blockOff[blockIdx.x] + lds[t] - tsum;
    int i0 = idx * 4;
    scanned[i0 + 0] = base;
    scanned[i0 + 1] = base + v.x;
    scanned[i0 + 2] = base + v.x + v.y;
    scanned[i0 + 3] = base + v.x + v.y + v.z;
}

// ---------------- 3. place packed (dstLocal<<17|src) into coarse buckets ----------------
__global__ __launch_bounds__(256) void binPlace_kernel(const int* __restrict__ src,
                                                       const int* __restrict__ dst,
                                                       const int* __restrict__ scanned,
                                                       int* __restrict__ packed)
{
    __shared__ int cur[NB];
    const int t = threadIdx.x, blk = blockIdx.x;
    for (int i = t; i < NB; i += 256) cur[i] = scanned[i * BC_BLOCKS + blk];
    __syncthreads();
    const int4* d4 = (const int4*)dst;
    const int4* s4 = (const int4*)src;
    const int base = blk * EPB4;
#pragma unroll
    for (int it = 0; it < 8; ++it) {
        int i = base + it * 256 + t;
        if (i < N_EDGES / 4) {
            int4 dv = d4[i];
            int4 sv = s4[i];
            int p0 = atomicAdd(&cur[dv.x >> 7], 1);
            packed[p0] = ((dv.x & 127) << 17) | sv.x;
            int p1 = atomicAdd(&cur[dv.y >> 7], 1);
            packed[p1] = ((dv.y & 127) << 17) | sv.y;
            int p2 = atomicAdd(&cur[dv.z >> 7], 1);
            packed[p2] = ((dv.z & 127) << 17) | sv.z;
            int p3 = atomicAdd(&cur[dv.w >> 7], 1);
            packed[p3] = ((dv.w & 127) << 17) | sv.w;
        }
    }
}

// ---------------- 4. fused in-LDS node sort + QUAD-lane bf16 gather ----------------
// one block per 128-node bucket, 512 threads = 8 waves.
// lane p in [0,16) owns features 4p..4p+3 (one uint2 of h16);
// side = lane>>4 in [0,4) takes every 4th edge; shfl_xor(16)+(32) combines.
// one wave-load instruction covers 4 edge-rows (512 B).
__global__ __launch_bounds__(512) void sortAgg_kernel(
    const uint2* __restrict__ h16v, const int* __restrict__ packed,
    const int* __restrict__ scanned, float* __restrict__ agg)
{
    __shared__ int edges[LDS_CAP];
    __shared__ int hist[128], scn[128], cur[128], offs[129];
    const int b = blockIdx.x, t = threadIdx.x;
    const int beg = scanned[b * BC_BLOCKS];
    const int end = scanned[(b + 1) * BC_BLOCKS];
    const int n = end - beg;

    if (t < 128) hist[t] = 0;
    __syncthreads();
    for (int i = t; i < n; i += 512)
        atomicAdd(&hist[packed[beg + i] >> 17], 1);
    __syncthreads();
    int v = (t < 128) ? hist[t] : 0;
    if (t < 128) scn[t] = v;
    __syncthreads();
    for (int off = 1; off < 128; off <<= 1) {
        int u = (t < 128 && t >= off) ? scn[t - off] : 0;
        __syncthreads();
        if (t < 128) scn[t] += u;
        __syncthreads();
    }
    if (t < 128) { offs[t] = scn[t] - v; cur[t] = scn[t] - v; }
    if (t == 0) offs[128] = n;
    __syncthreads();
    const bool fast = (n <= LDS_CAP);
    if (fast) {
        for (int i = t; i < n; i += 512) {
            int p = packed[beg + i];
            int pos = atomicAdd(&cur[p >> 17], 1);
            edges[pos] = p & SRC_MASK;
        }
    }
    __syncthreads();

    const int lane = t & 63, w = t >> 6;
    const int p = lane & 15;        // feature quad: 4p..4p+3
    const int side = lane >> 4;     // 0..3 within wave
    const int node0 = b << 7;

    for (int ln = w; ln < 128; ln += 8) {
        int node = node0 + ln;
        if (node >= N_NODES) break;  // ln monotone per wave
        float4 acc = make_float4(0.f, 0.f, 0.f, 0.f);
        if (fast) {
            const int o0 = offs[ln];
            const int cnt = offs[ln + 1] - o0;
            int j = side;
            for (; j + 12 < cnt; j += 16) {
                int s0 = edges[o0 + j];
                int s1 = edges[o0 + j + 4];
                int s2 = edges[o0 + j + 8];
                int s3 = edges[o0 + j + 12];
                uint2 u0 = h16v[s0 * 16 + p];
                uint2 u1 = h16v[s1 * 16 + p];
                uint2 u2 = h16v[s2 * 16 + p];
                uint2 u3 = h16v[s3 * 16 + p];
                acc.x += __uint_as_float(u0.x << 16);
                acc.y += __uint_as_float(u0.x & 0xFFFF0000u);
                acc.z += __uint_as_float(u0.y << 16);
                acc.w += __uint_as_float(u0.y & 0xFFFF0000u);
                acc.x += __uint_as_float(u1.x << 16);
                acc.y += __uint_as_float(u1.x & 0xFFFF0000u);
                acc.z += __uint_as_float(u1.y << 16);
                acc.w += __uint_as_float(u1.y & 0xFFFF0000u);
                acc.x += __uint_as_float(u2.x << 16);
                acc.y += __uint_as_float(u2.x & 0xFFFF0000u);
                acc.z += __uint_as_float(u2.y << 16);
                acc.w += __uint_as_float(u2.y & 0xFFFF0000u);
                acc.x += __uint_as_float(u3.x << 16);
                acc.y += __uint_as_float(u3.x & 0xFFFF0000u);
                acc.z += __uint_as_float(u3.y << 16);
                acc.w += __uint_as_float(u3.y & 0xFFFF0000u);
            }
            for (; j < cnt; j += 4) {
                uint2 u = h16v[edges[o0 + j] * 16 + p];
                acc.x += __uint_as_float(u.x << 16);
                acc.y += __uint_as_float(u.x & 0xFFFF0000u);
                acc.z += __uint_as_float(u.y << 16);
                acc.w += __uint_as_float(u.y & 0xFFFF0000u);
            }
        } else {
            // overflow fallback (statistically unreachable): filter-scan the run
            for (int i = side; i < n; i += 4) {
                int pk = packed[beg + i];
                if ((pk >> 17) == ln) {
                    uint2 u = h16v[(pk & SRC_MASK) * 16 + p];
                    acc.x += __uint_as_float(u.x << 16);
                    acc.y += __uint_as_float(u.x & 0xFFFF0000u);
                    acc.z += __uint_as_float(u.y << 16);
                    acc.w += __uint_as_float(u.y & 0xFFFF0000u);
                }
            }
        }
        acc.x += __shfl_xor(acc.x, 16);
        acc.y += __shfl_xor(acc.y, 16);
        acc.z += __shfl_xor(acc.z, 16);
        acc.w += __shfl_xor(acc.w, 16);
        acc.x += __shfl_xor(acc.x, 32);
        acc.y += __shfl_xor(acc.y, 32);
        acc.z += __shfl_xor(acc.z, 32);
        acc.w += __shfl_xor(acc.w, 32);
        if (side == 0)
            ((float4*)(agg + (size_t)node * IN_DIM))[p] = acc;
    }
}

// ---------------- 5. syrk: G-partials = agg^T agg, colsum partials ----------------
__global__ __launch_bounds__(256) void syrk_kernel(const float* __restrict__ agg,
                                                   float* __restrict__ Gp)
{
    __shared__ float As[32][64];
    const int t = threadIdx.x, blk = blockIdx.x;
    const int row_beg = blk * SYRK_ROWS;
    int row_end = row_beg + SYRK_ROWS;
    if (row_end > N_NODES) row_end = N_NODES;

    const int i0 = (t & 15) * 4, j0 = (t >> 4) * 4;
    float acc[4][4];
#pragma unroll
    for (int i = 0; i < 4; i++)
#pragma unroll
        for (int j = 0; j < 4; j++) acc[i][j] = 0.f;
    float cs = 0.f;

    for (int r0 = row_beg; r0 < row_end; r0 += 32) {
        int nrows = row_end - r0; if (nrows > 32) nrows = 32;
        for (int i = t; i < nrows * 16; i += 256)
            ((float4*)&As[0][0])[i] = ((const float4*)(agg + (size_t)r0 * IN_DIM))[i];
        __syncthreads();
        for (int r = 0; r < nrows; ++r) {
            float4 ai = *(const float4*)&As[r][i0];
            float4 aj = *(const float4*)&As[r][j0];
            acc[0][0] += ai.x * aj.x; acc[0][1] += ai.x * aj.y;
            acc[0][2] += ai.x * aj.z; acc[0][3] += ai.x * aj.w;
            acc[1][0] += ai.y * aj.x; acc[1][1] += ai.y * aj.y;
            acc[1][2] += ai.y * aj.z; acc[1][3] += ai.y * aj.w;
            acc[2][0] += ai.z * aj.x; acc[2][1] += ai.z * aj.y;
            acc[2][2] += ai.z * aj.z; acc[2][3] += ai.z * aj.w;
            acc[3][0] += ai.w * aj.x; acc[3][1] += ai.w * aj.y;
            acc[3][2] += ai.w * aj.z; acc[3][3] += ai.w * aj.w;
        }
        if (t < 64) {
            for (int r = 0; r < nrows; ++r) cs += As[r][t];
        }
        __syncthreads();
    }
    float* gp = Gp + (size_t)blk * GSZ;
#pragma unroll
    for (int i = 0; i < 4; i++)
#pragma unroll
        for (int j = 0; j < 4; j++)
            gp[(i0 + i) * 64 + (j0 + j)] = acc[i][j];
    if (t < 64) gp[4096 + t] = cs;
}

// ---------------- 6. reduce G partials ----------------
__global__ __launch_bounds__(256) void reduceG_kernel(const float* __restrict__ Gp,
                                                      float* __restrict__ G)
{
    int gid = blockIdx.x * 256 + threadIdx.x;
    if (gid < GSZ) {
        float s = 0.f;
        for (int b = 0; b < SYRK_BLOCKS; ++b) s += Gp[(size_t)b * GSZ + gid];
        G[gid] = s;
    }
}

// ---------------- 7. finalize: per-column scale/shift from G ----------------
__global__ __launch_bounds__(256) void finalize_kernel(
    const float* __restrict__ G, const float* __restrict__ W,
    const float* __restrict__ bias, const float* __restrict__ gamma,
    const float* __restrict__ beta, float* __restrict__ scale,
    float* __restrict__ shift)
{
    __shared__ float Gs[4096];
    __shared__ float ss[64];
    __shared__ float part[256];
    const int t = threadIdx.x;
    for (int i = t; i < 4096; i += 256) Gs[i] = G[i];
    if (t < 64) ss[t] = G[4096 + t];
    __syncthreads();

    const int c = t & 127, half = t >> 7;
    float wc[64];
#pragma unroll
    for (int k = 0; k < 64; ++k) wc[k] = W[k * HID + c];

    float p = 0.f;
    for (int k1 = 0; k1 < 32; ++k1) {
        int k1g = half * 32 + k1;
        float dot = 0.f;
#pragma unroll
        for (int k2 = 0; k2 < 64; ++k2) dot += Gs[k1g * 64 + k2] * wc[k2];
        p += W[k1g * HID + c] * dot;
    }
    part[t] = p;
    __syncthreads();
    if (half == 0) {
        float quad = part[c] + part[c + 128];  // w_c^T G w_c
        float tc = 0.f;
#pragma unroll
        for (int k = 0; k < 64; ++k) tc += ss[k] * wc[k];
        const float invN = 1.0f / (float)N_NODES;
        float bc   = bias[c];
        float mean = tc * invN + bc;
        float ez2  = quad * invN + 2.f * bc * tc * invN + bc * bc;
        float var  = ez2 - mean * mean;
        float inv  = rsqrtf(var + BN_EPS);
        float scv  = gamma[c] * inv;
        scale[c] = scv;
        shift[c] = beta[c] - mean * scv;
    }
}

// ---------------- 8. GEMM + scale/shift: LDS W + transposed-A, 4x4 per thread ----------------
#define AST_LD 36   // row stride of Ast in floats (144 B: 16B-aligned, odd bank group)
__global__ __launch_bounds__(256) void gemm_out_kernel(
    const float* __restrict__ agg, const float* __restrict__ W,
    const float* __restrict__ scale, const float* __restrict__ shift,
    float* __restrict__ out)
{
    __shared__ float Ws[IN_DIM][HID];        // 32 KB
    __shared__ float Ast[IN_DIM][AST_LD];    // 9 KB, Ast[k][row]
    const int t = threadIdx.x;
    const int tile = blockIdx.x;
    const int rowbase = tile * 32;

    {
        const float4* s4 = (const float4*)W;
        float4* d4 = (float4*)&Ws[0][0];
#pragma unroll
        for (int i = 0; i < (IN_DIM * HID / 4) / 256; ++i)
            d4[t + i * 256] = s4[t + i * 256];
    }
    {
        const float4* s4 = (const float4*)(agg + (size_t)rowbase * IN_DIM);
#pragma unroll
        for (int it = 0; it < 2; ++it) {
            int l = t + it * 256;
            float4 a = s4[l];
            int row = l >> 4, kg = (l & 15) * 4;
            Ast[kg + 0][row] = a.x;
            Ast[kg + 1][row] = a.y;
            Ast[kg + 2][row] = a.z;
            Ast[kg + 3][row] = a.w;
        }
    }
    __syncthreads();

    const int c4 = (t & 31) * 4;
    const int r0 = (t >> 5) * 4;

    float acc[4][4];
#pragma unroll
    for (int i = 0; i < 4; i++)
#pragma unroll
        for (int j = 0; j < 4; j++) acc[i][j] = 0.f;

#pragma unroll 8
    for (int k = 0; k < IN_DIM; ++k) {
        float4 w4 = *(const float4*)&Ws[k][c4];
        float4 a4 = *(const float4*)&Ast[k][r0];
        acc[0][0] += a4.x * w4.x; acc[0][1] += a4.x * w4.y;
        acc[0][2] += a4.x * w4.z; acc[0][3] += a4.x * w4.w;
        acc[1][0] += a4.y * w4.x; acc[1][1] += a4.y * w4.y;
        acc[1][2] += a4.y * w4.z; acc[1][3] += a4.y * w4.w;
        acc[2][0] += a4.z * w4.x; acc[2][1] += a4.z * w4.y;
        acc[2][2] += a4.z * w4.z; acc[2][3] += a4.z * w4.w;
        acc[3][0] += a4.w * w4.x; acc[3][1] += a4.w * w4.y;
        acc[3][2] += a4.w * w4.z; acc[3][3] += a4.w * w4.w;
    }

    const float4 sc4 = ((const float4*)scale)[t & 31];
    const float4 sh4 = ((const float4*)shift)[t & 31];
#pragma unroll
    for (int i = 0; i < 4; ++i) {
        float4 o;
        o.x = acc[i][0] * sc4.x + sh4.x;
        o.y = acc[i][1] * sc4.y + sh4.y;
        o.z = acc[i][2] * sc4.z + sh4.z;
        o.w = acc[i][3] * sc4.w + sh4.w;
        *(float4*)&out[(size_t)(rowbase + r0 + i) * HID + c4] = o;
    }
}

extern "C" void kernel_launch(void* const* d_in, const int* in_sizes, int n_in,
                              void* d_out, int out_size, void* d_ws, size_t ws_size,
                              hipStream_t stream)
{
    const float* h     = (const float*)d_in[0];
    const int*   src   = (const int*)d_in[1];
    const int*   dst   = (const int*)d_in[2];
    const float* W     = (const float*)d_in[3];
    const float* b     = (const float*)d_in[4];
    const float* gamma = (const float*)d_in[5];
    const float* beta  = (const float*)d_in[6];

    float* out = (float*)d_out;

    // ---- workspace layout ----
    float* agg  = (float*)d_ws;
    unsigned short* h16 = (unsigned short*)(agg + (size_t)N_NODES * IN_DIM);
    float* G     = (float*)(h16 + (size_t)N_NODES * IN_DIM);
    float* scale = G + GSZ;
    float* shift = scale + HID;
    int*  counts    = (int*)(shift + HID);
    int*  blockSums = counts + SC_PAD;
    int*  blockOff  = blockSums + 256;
    int*  scanned   = blockOff + 256;
    int*  packed    = scanned + SC_PAD;          // N_EDGES ints
    float* Gp       = (float*)counts;            // aliases sort transients (dead by syrk)

    count_conv_kernel<<<BC_BLOCKS + CONV_BLOCKS + 1, 256, 0, stream>>>(dst, counts,
                                                                       h, h16);
    scanA_kernel<<<SC_NBLK, 256, 0, stream>>>(counts, blockSums);
    scanB_kernel<<<1, 256, 0, stream>>>(blockSums, blockOff);
    scanC_kernel<<<SC_NBLK, 256, 0, stream>>>(counts, blockOff, scanned);
    binPlace_kernel<<<BC_BLOCKS, 256, 0, stream>>>(src, dst, scanned, packed);
    sortAgg_kernel<<<NB, 512, 0, stream>>>((const uint2*)h16, packed, scanned, agg);
    syrk_kernel<<<SYRK_BLOCKS, 256, 0, stream>>>(agg, Gp);
    reduceG_kernel<<<(GSZ + 255) / 256, 256, 0, stream>>>(Gp, G);
    finalize_kernel<<<1, 256, 0, stream>>>(G, W, b, gamma, beta, scale, shift);
    gemm_out_kernel<<<N_NODES / 32, 256, 0, stream>>>(agg, W, scale, shift, out);
}